// Round 4
// baseline (128.618 us; speedup 1.0000x reference)
//
#include <hip/hip_runtime.h>

// FeatureEmbedder: out[b, f*64+d] = relu(x[b,f] * W[f,d] + b[f,d])
// x: [16384, 128] f32, W: [128, 64] f32, b: [128, 64] f32
// out: [16384, 8192] f32  (512 MB -> HBM-write-bound)
//
// R4: decouple x loads from the store stream. vmcnt retires in issue order,
// so interleaved load->fma->store chains make every load-wait transitively
// wait on prior STORE acks (HBM-paced). Stage the block's 4 KB x-tile in LDS
// once; the main loop then reads x via lgkmcnt (ds_read broadcast) and the
// vmcnt FIFO carries pure stores -- structurally identical to the 6.7 TB/s
// fill kernel. nt reverted (R3 refuted the L2-pollution theory).

#define BATCH 16384
#define NFEAT 128
#define EMBD  64
#define ROW4  (NFEAT * EMBD / 4)   // 2048 float4 per output row

typedef float vfloat4 __attribute__((ext_vector_type(4)));

__global__ __launch_bounds__(256) void feature_embed_kernel(
    const float* __restrict__ x,
    const vfloat4* __restrict__ W4,
    const vfloat4* __restrict__ B4,
    vfloat4* __restrict__ out4) {

    // Block geometry: block b owns col4 range [(b&7)*256, +256) and rows
    // r0, r0+256, ..., r0+256*63 where r0 = b>>3.  (2048 blocks total)
    __shared__ float xs[64][16];          // [iter][feature-within-block]

    const int tid     = threadIdx.x;      // 0..255
    const int b       = blockIdx.x;       // 0..2047
    const int colBase = (b & 7) * 256;    // col4 base for this block
    const int col4    = colBase + tid;    // loop-invariant output column
    const int r0      = b >> 3;           // starting row, 0..255
    const int f0      = colBase >> 4;     // first of this block's 16 features

    // Stage x[r0 + 256*i, f0 .. f0+15] for i = 0..63 (4 KB) into LDS.
    // Round k: thread t loads iter i = k*16 + (t>>4), feature t&15.
    #pragma unroll
    for (int k = 0; k < 4; ++k) {
        const int i    = k * 16 + (tid >> 4);
        const int feat = tid & 15;
        xs[i][feat] = x[(r0 + (i << 8)) * NFEAT + f0 + feat];
    }

    // W/b are tiny and the column is fixed -> hoist (vmcnt drains here, before
    // the store loop begins).
    const vfloat4 w  = W4[col4];
    const vfloat4 bb = B4[col4];
    __syncthreads();

    const int fl = tid >> 4;              // feature index within block, 0..15

    #pragma unroll 8
    for (int i = 0; i < 64; ++i) {
        const float xv = xs[i][fl];       // ds_read, 16-lane broadcast
        vfloat4 o;
        o.x = fmaxf(fmaf(xv, w.x, bb.x), 0.0f);
        o.y = fmaxf(fmaf(xv, w.y, bb.y), 0.0f);
        o.z = fmaxf(fmaf(xv, w.z, bb.z), 0.0f);
        o.w = fmaxf(fmaf(xv, w.w, bb.w), 0.0f);
        // Pure-store vmcnt stream: 64 lanes x 16 B = 1 KB coalesced.
        out4[((r0 + (i << 8)) << 11) + col4] = o;
    }
}

extern "C" void kernel_launch(void* const* d_in, const int* in_sizes, int n_in,
                              void* d_out, int out_size, void* d_ws, size_t ws_size,
                              hipStream_t stream) {
    const float*   x  = (const float*)d_in[0];
    const vfloat4* W4 = (const vfloat4*)d_in[1];
    const vfloat4* B4 = (const vfloat4*)d_in[2];
    vfloat4* out4     = (vfloat4*)d_out;

    feature_embed_kernel<<<2048, 256, 0, stream>>>(x, W4, B4, out4);
}

// Round 5
// 101.958 us; speedup vs baseline: 1.2615x; 1.2615x over previous
//
#include <hip/hip_runtime.h>

// FeatureEmbedder: out[b, f*64+d] = relu(x[b,f] * W[f,d] + b[f,d])
// x: [16384, 128] f32, W: [128, 64] f32, b: [128, 64] f32
// out: [16384, 8192] f32  (512 MB -> HBM-write-bound)
//
// R5: DRAM page locality for the write stream. Previous kernels fixed each
// thread's column and strode rows by 256 -> a wave's consecutive stores were
// 8 MB apart (new DRAM page every store; ~2048 drifting streams thrash the
// channels). fillBufferAligned hits 6.7-6.9 TB/s at 10.6% occupancy with
// linear streams. Here block b owns a CONTIGUOUS 1 MB of out (rows 32b..+31)
// and sweeps it linearly in 4 KB chunks; only 512 blocks = few long linear
// write streams. Column pattern per thread cycles through 8 values -> hoist
// 8 (w,b) float4 pairs in registers; x-tile (16 KB) staged once in LDS.

#define BATCH 16384
#define NFEAT 128
#define EMBD  64
#define ROW4  (NFEAT * EMBD / 4)   // 2048 float4 per output row

typedef float vfloat4 __attribute__((ext_vector_type(4)));

__global__ __launch_bounds__(256) void feature_embed_kernel(
    const vfloat4* __restrict__ x4,
    const vfloat4* __restrict__ W4,
    const vfloat4* __restrict__ B4,
    vfloat4* __restrict__ out4) {

    __shared__ float xs[32 * NFEAT];      // 16 KB: x rows 32b .. 32b+31

    const int tid = threadIdx.x;          // 0..255
    const int b   = blockIdx.x;           // 0..511

    // Per-thread column set: col4 = j*256 + tid, j = 0..7. Hoist W/b.
    vfloat4 w[8], bb[8];
    #pragma unroll
    for (int j = 0; j < 8; ++j) {
        w[j]  = W4[j * 256 + tid];
        bb[j] = B4[j * 256 + tid];
    }

    // Stage x rows 32b..32b+31 (4096 floats = 1024 float4, contiguous in x).
    #pragma unroll
    for (int k = 0; k < 4; ++k)
        ((vfloat4*)xs)[k * 256 + tid] = x4[b * 1024 + k * 256 + tid];
    __syncthreads();

    const int fs = tid >> 4;              // within-j feature sub-index, 0..15
    vfloat4* outb = out4 + b * 32 * ROW4; // this block's 1 MB region

    #pragma unroll 4
    for (int r = 0; r < 32; ++r) {
        const float* xr = xs + r * NFEAT;
        #pragma unroll
        for (int j = 0; j < 8; ++j) {
            const float xv = xr[j * 16 + fs];     // ds_read broadcast
            vfloat4 o;
            o.x = fmaxf(fmaf(xv, w[j].x, bb[j].x), 0.0f);
            o.y = fmaxf(fmaf(xv, w[j].y, bb[j].y), 0.0f);
            o.z = fmaxf(fmaf(xv, w[j].z, bb[j].z), 0.0f);
            o.w = fmaxf(fmaf(xv, w[j].w, bb[j].w), 0.0f);
            // Linear sweep: iteration (r*8+j) writes the next 4 KB chunk.
            outb[(r * 8 + j) * 256 + tid] = o;
        }
    }
}

extern "C" void kernel_launch(void* const* d_in, const int* in_sizes, int n_in,
                              void* d_out, int out_size, void* d_ws, size_t ws_size,
                              hipStream_t stream) {
    const vfloat4* x4 = (const vfloat4*)d_in[0];
    const vfloat4* W4 = (const vfloat4*)d_in[1];
    const vfloat4* B4 = (const vfloat4*)d_in[2];
    vfloat4* out4     = (vfloat4*)d_out;

    // 512 blocks x 256 threads; block b writes rows [32b, 32b+32) linearly.
    feature_embed_kernel<<<512, 256, 0, stream>>>(x4, W4, B4, out4);
}